// Round 4
// baseline (2775.782 us; speedup 1.0000x reference)
//
#include <hip/hip_runtime.h>

// NTM controller B=64,T=512,I=64,H=256,O=64. Memory module provably dead
// (mem0=0 -> lw=0 -> add=tanh(0)=0 -> mem stays 0, read_vec=0), so:
//   LSTM recurrence + out = h @ W_dec[:, :256]^T + b_dec.
// Phase 1 (xproj): XP[b,t,:] = x@W_ih^T + b_ih + b_hh. 256 blocks x 512 thr.
// Phase 2 (rec): 64 blocks (1/batch) x 256 threads, 1 wave/SIMD pinned via
//   amdgpu_waves_per_eu(1,1) => 512-VGPR budget (launch_bounds minimums let the
//   compiler raise occupancy and spill: rounds 1-3 all allocated 128).
// Thread tid owns hidden unit tid: gate rows tid,tid+256,tid+512,tid+768.
// W_hh fp16: slices [0,184) in VGPRs (4x92 f16x2), [184,256) in LDS as
// [144][256] uint (b32 conflict-free). h fp16 double-buffered in LDS, read as
// uniform b128 broadcasts. One barrier per step. Decode pipelined one step.

typedef _Float16 f16x2 __attribute__((ext_vector_type(2)));

#define NB  64
#define TT  512
#define HH  256
#define KR  184     // k-slices of W_hh in registers
#define PRW 92      // f16x2 pairs per row in regs
#define QR  23      // h-quads (8 slices each) for reg part
#define LPR 36      // LDS pairs per row
#define QL  9       // h-quads for LDS part
#define WROWS 144   // LPR*4

union U32H { unsigned int u; f16x2 h; };
static __device__ __forceinline__ unsigned int pack2f(float a, float b) {
    U32H v; v.h = f16x2{(_Float16)a, (_Float16)b}; return v.u;
}
static __device__ __forceinline__ f16x2 up(unsigned int u) { U32H v; v.u = u; return v.h; }

__device__ __forceinline__ float sigf(float x) { return 1.0f / (1.0f + __expf(-x)); }
__device__ __forceinline__ float tanhfast(float x) {
    float e = __expf(2.0f * x);
    return 1.0f - 2.0f / (e + 1.0f);
}

#if __has_builtin(__builtin_amdgcn_fdot2)
__device__ __forceinline__ float dot2(f16x2 a, f16x2 b, float c) {
    return __builtin_amdgcn_fdot2(a, b, c, false);
}
#else
__device__ __forceinline__ float dot2(f16x2 a, f16x2 b, float c) {
    return c + (float)a.x * (float)b.x + (float)a.y * (float)b.y;
}
#endif

// ---------------- phase 1: x-projection ----------------
__global__ void __launch_bounds__(512)
xproj_kernel(const float* __restrict__ x_seq, const float* __restrict__ W_ih,
             const float* __restrict__ b_ih, const float* __restrict__ b_hh,
             float* __restrict__ XP)
{
    __shared__ float xs[128 * 64];            // 32 KB x chunk (fp32)
    const int tid = threadIdx.x;
    const int b   = blockIdx.x >> 2;
    const int q   = blockIdx.x & 3;

    const float* xb = x_seq + ((size_t)b * TT + (size_t)q * 128) * 64;
#pragma unroll
    for (int i = 0; i < 4; ++i)
        *(float4*)(xs + tid * 16 + 4 * i) = *(const float4*)(xb + tid * 16 + 4 * i);

    // rows tid, tid+512 as f16 pairs: 64 uint regs (fits the 128-VGPR default cap)
    unsigned int w0p[32], w1p[32];
    const float* r0 = W_ih + (size_t)tid * 64;
    const float* r1 = W_ih + (size_t)(tid + 512) * 64;
#pragma unroll
    for (int i = 0; i < 16; ++i) {
        float4 v0 = *(const float4*)(r0 + 4 * i);
        float4 v1 = *(const float4*)(r1 + 4 * i);
        w0p[2*i] = pack2f(v0.x, v0.y); w0p[2*i+1] = pack2f(v0.z, v0.w);
        w1p[2*i] = pack2f(v1.x, v1.y); w1p[2*i+1] = pack2f(v1.z, v1.w);
    }
    const float bias0 = b_ih[tid]       + b_hh[tid];
    const float bias1 = b_ih[tid + 512] + b_hh[tid + 512];
    __syncthreads();

    float* xpb = XP + ((size_t)b * TT + (size_t)q * 128) * 1024;
    for (int tt = 0; tt < 128; ++tt) {
        const float* xr = xs + tt * 64;
        float a0 = bias0, a1 = bias1;
        float a2 = 0.f, a3 = 0.f, a4 = 0.f, a5 = 0.f, a6 = 0.f, a7 = 0.f;
#pragma unroll
        for (int k = 0; k < 64; k += 4) {
            const int p = k >> 1;
            float x0 = xr[k], x1 = xr[k+1], x2 = xr[k+2], x3 = xr[k+3];
            a0 += (float)up(w0p[p]).x   * x0;  a1 += (float)up(w1p[p]).x   * x0;
            a2 += (float)up(w0p[p]).y   * x1;  a3 += (float)up(w1p[p]).y   * x1;
            a4 += (float)up(w0p[p+1]).x * x2;  a5 += (float)up(w1p[p+1]).x * x2;
            a6 += (float)up(w0p[p+1]).y * x3;  a7 += (float)up(w1p[p+1]).y * x3;
        }
        xpb[tt * 1024 + tid]       = (a0 + a2) + (a4 + a6);
        xpb[tt * 1024 + tid + 512] = (a1 + a3) + (a5 + a7);
    }
}

// ---------------- phase 2: recurrence ----------------
// LDS: wl uint[144][256] (147456 B) | hbufq uint4[2][32] (1024 B) | x_lds float[64]
template <bool USE_XP>
__global__ void
__attribute__((amdgpu_flat_work_group_size(256, 256), amdgpu_waves_per_eu(1, 1)))
ntm_rec(const float* __restrict__ x_seq,
        const float* __restrict__ W_ih,
        const float* __restrict__ b_ih,
        const float* __restrict__ b_hh,
        const float* __restrict__ XP,
        const float* __restrict__ W_hh,
        const float* __restrict__ W_dec,
        const float* __restrict__ b_dec,
        float* __restrict__ out)
{
    extern __shared__ char smem[];
    unsigned int* wl    = (unsigned int*)smem;                        // [144][256]
    uint4*        hbufq = (uint4*)(smem + (size_t)WROWS * 256 * 4);   // [2][32]
    float*        x_lds = (float*)(smem + (size_t)WROWS * 256 * 4 + 1024);

    const int tid = threadIdx.x;
    const int b   = blockIdx.x;

    // ---- resident weights: rows tid+256r (r=0:i,1:f,2:g,3:o), slices<KR in regs ----
    f16x2 wr[4][PRW];
#pragma unroll
    for (int r = 0; r < 4; ++r) {
        const float* row = W_hh + (size_t)(tid + 256 * r) * HH;
#pragma unroll
        for (int p2 = 0; p2 < 64; ++p2) {       // float4 = slices 4p2..4p2+3
            float4 v = *(const float4*)(row + 4 * p2);
            if (p2 < 46) {                       // slices < 184 -> regs
                wr[r][2*p2]   = up(pack2f(v.x, v.y));
                wr[r][2*p2+1] = up(pack2f(v.z, v.w));
            } else {                             // slices >= 184 -> LDS
                const int lp = 2 * p2 - 92;      // 0..34 even
                wl[(r * LPR + lp)     * 256 + tid] = pack2f(v.x, v.y);
                wl[(r * LPR + lp + 1) * 256 + tid] = pack2f(v.z, v.w);
            }
        }
    }

    // ---- decode weights: o = wave*16 + (lane>>2), c = lane&3 covers 64 slices ----
    const int lane = tid & 63, wv = tid >> 6;
    const int o = wv * 16 + (lane >> 2), c = lane & 3;
    unsigned int wdq[32];
    {
        const float* wd = W_dec + (size_t)o * 384 + c * 64;
#pragma unroll
        for (int i = 0; i < 32; ++i) {
            float2 v = *(const float2*)(wd + 2 * i);
            wdq[i] = pack2f(v.x, v.y);
        }
    }
    const float bdec = b_dec[o];

    float bias[4] = {0.f, 0.f, 0.f, 0.f};
    if (!USE_XP) {
#pragma unroll
        for (int r = 0; r < 4; ++r) bias[r] = b_ih[tid + 256*r] + b_hh[tid + 256*r];
    }

    if (tid < 64) ((uint4*)hbufq)[tid] = make_uint4(0u, 0u, 0u, 0u);  // h=0 both bufs
    float c_state = 0.f;
    __syncthreads();

    const float* xpb  = XP    + (size_t)b * TT * 1024;
    const float* xb   = x_seq + (size_t)b * TT * 64;
    float*       outb = out   + (size_t)b * TT * 64;

    float xc[4];
    if (USE_XP) {
#pragma unroll
        for (int r = 0; r < 4; ++r) xc[r] = xpb[tid + 256 * r];
    }

    for (int t = 0; t < TT; ++t) {
        const uint4* hq = hbufq + ((t & 1) << 5);   // h_{t-1}

        // ---- decode out[t-1] (pipelined; reads h_{t-1}) ----
        if (t > 0) {
            float dacc = 0.f;
#pragma unroll
            for (int i = 0; i < 8; ++i) {
                uint4 hv = hq[c * 8 + i];
                dacc = dot2(up(wdq[4*i]),   up(hv.x), dacc);
                dacc = dot2(up(wdq[4*i+1]), up(hv.y), dacc);
                dacc = dot2(up(wdq[4*i+2]), up(hv.z), dacc);
                dacc = dot2(up(wdq[4*i+3]), up(hv.w), dacc);
            }
            dacc += __shfl_xor(dacc, 1);
            dacc += __shfl_xor(dacc, 2);
            if (c == 0) outb[(t - 1) * 64 + o] = dacc + bdec;
        }

        float xn[4];
        if (USE_XP) {
            if (t + 1 < TT) {
#pragma unroll
                for (int r = 0; r < 4; ++r)
                    xn[r] = xpb[(size_t)(t + 1) * 1024 + tid + 256 * r];
            }
        }

        float a[4][4];
#pragma unroll
        for (int r = 0; r < 4; ++r) {
            a[r][0] = USE_XP ? xc[r] : bias[r];
            a[r][1] = 0.f; a[r][2] = 0.f; a[r][3] = 0.f;
        }

        if (!USE_XP) {   // fallback: stream x@W_ih from global (slow, correct)
            if (tid < 64) x_lds[tid] = xb[t * 64 + tid];
            __syncthreads();
            for (int k = 0; k < 64; ++k) {
                float xv = x_lds[k];
#pragma unroll
                for (int r = 0; r < 4; ++r)
                    a[r][0] += W_ih[(size_t)(tid + 256*r) * 64 + k] * xv;
            }
        }

        // ---- h @ W_hh^T, register-resident slices [0,184) ----
#pragma unroll
        for (int q = 0; q < QR; ++q) {
            uint4 hv = hq[q];
            f16x2 h0 = up(hv.x), h1 = up(hv.y), h2 = up(hv.z), h3 = up(hv.w);
#pragma unroll
            for (int r = 0; r < 4; ++r) {
                a[r][0] = dot2(wr[r][4*q],   h0, a[r][0]);
                a[r][1] = dot2(wr[r][4*q+1], h1, a[r][1]);
                a[r][2] = dot2(wr[r][4*q+2], h2, a[r][2]);
                a[r][3] = dot2(wr[r][4*q+3], h3, a[r][3]);
            }
        }
        // ---- h @ W_hh^T, LDS-resident slices [184,256) ----
#pragma unroll
        for (int q = 0; q < QL; ++q) {
            uint4 hv = hq[QR + q];
            f16x2 h0 = up(hv.x), h1 = up(hv.y), h2 = up(hv.z), h3 = up(hv.w);
#pragma unroll
            for (int r = 0; r < 4; ++r) {
                const int base = (r * LPR + 4 * q) * 256 + tid;
                a[r][0] = dot2(up(wl[base]),       h0, a[r][0]);
                a[r][1] = dot2(up(wl[base + 256]), h1, a[r][1]);
                a[r][2] = dot2(up(wl[base + 512]), h2, a[r][2]);
                a[r][3] = dot2(up(wl[base + 768]), h3, a[r][3]);
            }
        }

        const float gi = (a[0][0] + a[0][1]) + (a[0][2] + a[0][3]);
        const float gf = (a[1][0] + a[1][1]) + (a[1][2] + a[1][3]);
        const float gg = (a[2][0] + a[2][1]) + (a[2][2] + a[2][3]);
        const float go = (a[3][0] + a[3][1]) + (a[3][2] + a[3][3]);

        c_state = sigf(gf) * c_state + sigf(gi) * tanhfast(gg);
        const float hn = sigf(go) * tanhfast(c_state);
        ((_Float16*)(hbufq + (((t + 1) & 1) << 5)))[tid] = (_Float16)hn;

        if (USE_XP) {
#pragma unroll
            for (int r = 0; r < 4; ++r) xc[r] = xn[r];
        }
        __syncthreads();   // h_t published; next iter reads it (writes go to other buf)
    }

    // ---- final decode: out[511] from h_511 (in hbufq[0]) ----
    {
        const uint4* hq = hbufq;   // (TT)&1 == 0
        float dacc = 0.f;
#pragma unroll
        for (int i = 0; i < 8; ++i) {
            uint4 hv = hq[c * 8 + i];
            dacc = dot2(up(wdq[4*i]),   up(hv.x), dacc);
            dacc = dot2(up(wdq[4*i+1]), up(hv.y), dacc);
            dacc = dot2(up(wdq[4*i+2]), up(hv.z), dacc);
            dacc = dot2(up(wdq[4*i+3]), up(hv.w), dacc);
        }
        dacc += __shfl_xor(dacc, 1);
        dacc += __shfl_xor(dacc, 2);
        if (c == 0) outb[(TT - 1) * 64 + o] = dacc + bdec;
    }
}

extern "C" void kernel_launch(void* const* d_in, const int* in_sizes, int n_in,
                              void* d_out, int out_size, void* d_ws, size_t ws_size,
                              hipStream_t stream) {
    const float* x_seq = (const float*)d_in[0];
    const float* W_ih  = (const float*)d_in[1];
    const float* W_hh  = (const float*)d_in[2];
    const float* b_ih  = (const float*)d_in[3];
    const float* b_hh  = (const float*)d_in[4];
    // d_in[5..8] unused: mem == 0 forever
    const float* W_dec = (const float*)d_in[9];
    const float* b_dec = (const float*)d_in[10];
    float* out = (float*)d_out;

    const size_t smem_bytes = (size_t)WROWS * 256 * 4 + 1024 + 256;  // 148736 B
    const size_t xp_bytes   = (size_t)NB * TT * 1024 * 4;            // 134 MB

    if (ws_size >= xp_bytes) {
        float* XP = (float*)d_ws;
        hipLaunchKernelGGL(xproj_kernel, dim3(256), dim3(512), 0, stream,
                           x_seq, W_ih, b_ih, b_hh, XP);
        hipFuncSetAttribute((const void*)&ntm_rec<true>,
                            hipFuncAttributeMaxDynamicSharedMemorySize, (int)smem_bytes);
        hipLaunchKernelGGL(ntm_rec<true>, dim3(NB), dim3(256), smem_bytes, stream,
                           x_seq, W_ih, b_ih, b_hh, XP, W_hh, W_dec, b_dec, out);
    } else {
        hipFuncSetAttribute((const void*)&ntm_rec<false>,
                            hipFuncAttributeMaxDynamicSharedMemorySize, (int)smem_bytes);
        hipLaunchKernelGGL(ntm_rec<false>, dim3(NB), dim3(256), smem_bytes, stream,
                           x_seq, W_ih, b_ih, b_hh, (const float*)nullptr,
                           W_hh, W_dec, b_dec, out);
    }
}

// Round 5
// 1166.603 us; speedup vs baseline: 2.3794x; 2.3794x over previous
//
#include <hip/hip_runtime.h>

// NTM controller B=64,T=512,I=64,H=256,O=64. Memory module provably dead
// (mem0=0 -> lw=0 -> add=tanh(0)=0 -> mem stays 0, read_vec=0), so:
//   LSTM recurrence + out = h @ W_dec[:, :256]^T + b_dec.
//
// Learned constraints (rounds 1-4):
//  - gfx950 max ADDRESSABLE VGPRs/thread = 256 (rest of unified file is AGPR-only).
//  - __launch_bounds__ does NOT pin the allocator; amdgpu_waves_per_eu(n,n) does.
//  - => 512 threads, 2 gate rows/thread, waves_per_eu(2,2): demand ~240 regs, no spill,
//    2 waves/SIMD for latency hiding.
// W_hh fp16: slices [0,184) in VGPRs (2x92 f16x2/thread), [184,256) in LDS as
// [18][512] uint4 (16 B/lane contiguous => conflict-free b128). h fp16 in LDS,
// uniform b128 broadcast reads. XP (x-projection + biases) precomputed packed f16x2:
// XPp[b][t][tid] = (gate row tid, gate row tid+512) -- 67 MB, L3-resident.

typedef _Float16 f16x2 __attribute__((ext_vector_type(2)));

#define NB 64
#define TT 512
#define HH 256
#define KR 184            // k-slices of W_hh in registers
#define PRW 92            // f16x2 pairs per row in regs (KR/2)
#define QR 23             // h-quads (8 slices each) covering reg part
#define GL 18             // LDS k-groups of 4 slices ((256-KR)/4)
#define QL 9              // h-quads covering LDS part

union U32H { unsigned int u; f16x2 h; };
static __device__ __forceinline__ unsigned int pack2f(float a, float b) {
    U32H v; v.h = f16x2{(_Float16)a, (_Float16)b}; return v.u;
}
static __device__ __forceinline__ f16x2 up(unsigned int u) { U32H v; v.u = u; return v.h; }

__device__ __forceinline__ float sigf(float x) { return 1.0f / (1.0f + __expf(-x)); }
__device__ __forceinline__ float tanhfast(float x) {
    float e = __expf(2.0f * x);
    return 1.0f - 2.0f / (e + 1.0f);
}

#if __has_builtin(__builtin_amdgcn_fdot2)
__device__ __forceinline__ float dot2(f16x2 a, f16x2 b, float c) {
    return __builtin_amdgcn_fdot2(a, b, c, false);
}
#else
__device__ __forceinline__ float dot2(f16x2 a, f16x2 b, float c) {
    return c + (float)a.x * (float)b.x + (float)a.y * (float)b.y;
}
#endif

// ---------------- phase 1: x-projection (packed f16x2 output) ----------------
// XPp[b][t][j] = pack( bias+x.Wih row j , row j+512 ), j = tid in [0,512)
__global__ void __attribute__((amdgpu_flat_work_group_size(512, 512)))
xproj_kernel(const float* __restrict__ x_seq, const float* __restrict__ W_ih,
             const float* __restrict__ b_ih, const float* __restrict__ b_hh,
             unsigned int* __restrict__ XPp)
{
    __shared__ unsigned int xq[128 * 32];     // 16 KB: x chunk packed f16 pairs
    const int tid = threadIdx.x;
    const int b   = blockIdx.x >> 2;
    const int q   = blockIdx.x & 3;

    // stage x: thread covers t-row tid>>2, 16-float segment (tid&3)
    {
        const float* src = x_seq + ((size_t)b * TT + (size_t)q * 128 + (tid >> 2)) * 64
                         + (tid & 3) * 16;
        unsigned int* dst = xq + (tid >> 2) * 32 + (tid & 3) * 8;
#pragma unroll
        for (int i = 0; i < 4; ++i) {
            float4 v = ((const float4*)src)[i];
            dst[2 * i]     = pack2f(v.x, v.y);
            dst[2 * i + 1] = pack2f(v.z, v.w);
        }
    }

    // weight rows tid, tid+512 packed f16x2: 64 regs
    unsigned int w0p[32], w1p[32];
    {
        const float* r0 = W_ih + (size_t)tid * 64;
        const float* r1 = W_ih + (size_t)(tid + 512) * 64;
#pragma unroll
        for (int i = 0; i < 16; ++i) {
            float4 v0 = *(const float4*)(r0 + 4 * i);
            float4 v1 = *(const float4*)(r1 + 4 * i);
            w0p[2*i] = pack2f(v0.x, v0.y); w0p[2*i+1] = pack2f(v0.z, v0.w);
            w1p[2*i] = pack2f(v1.x, v1.y); w1p[2*i+1] = pack2f(v1.z, v1.w);
        }
    }
    const float bias0 = b_ih[tid]       + b_hh[tid];
    const float bias1 = b_ih[tid + 512] + b_hh[tid + 512];
    __syncthreads();

    unsigned int* xpb = XPp + ((size_t)b * TT + (size_t)q * 128) * 512;
    for (int tt = 0; tt < 128; ++tt) {
        const uint4* xr = (const uint4*)(xq + tt * 32);
        float a0 = bias0, a1 = bias1;
        float a2 = 0.f, a3 = 0.f, a4 = 0.f, a5 = 0.f, a6 = 0.f, a7 = 0.f;
#pragma unroll
        for (int i = 0; i < 8; ++i) {
            uint4 xv = xr[i];
            a0 = dot2(up(w0p[4*i]),   up(xv.x), a0);  a1 = dot2(up(w1p[4*i]),   up(xv.x), a1);
            a2 = dot2(up(w0p[4*i+1]), up(xv.y), a2);  a3 = dot2(up(w1p[4*i+1]), up(xv.y), a3);
            a4 = dot2(up(w0p[4*i+2]), up(xv.z), a4);  a5 = dot2(up(w1p[4*i+2]), up(xv.z), a5);
            a6 = dot2(up(w0p[4*i+3]), up(xv.w), a6);  a7 = dot2(up(w1p[4*i+3]), up(xv.w), a7);
        }
        const float gA = (a0 + a2) + (a4 + a6);
        const float gB = (a1 + a3) + (a5 + a7);
        xpb[tt * 512 + tid] = pack2f(gA, gB);
    }
}

// ---------------- phase 2: recurrence ----------------
// LDS: whh4 uint4[18][512] (147456 B) | fo float[512] | h16 _Float16[256] | x_lds float[64]
template <bool USE_XP>
__global__ void
__attribute__((amdgpu_flat_work_group_size(512, 512), amdgpu_waves_per_eu(2, 2)))
ntm_rec(const float* __restrict__ x_seq,
        const float* __restrict__ W_ih,
        const float* __restrict__ b_ih,
        const float* __restrict__ b_hh,
        const unsigned int* __restrict__ XPp,
        const float* __restrict__ W_hh,
        const float* __restrict__ W_dec,
        const float* __restrict__ b_dec,
        float* __restrict__ out)
{
    extern __shared__ char smem[];
    uint4*    whh4  = (uint4*)smem;                                   // [18][512]
    float*    fo    = (float*)(smem + (size_t)GL * 512 * 16);         // [512]
    _Float16* h16   = (_Float16*)(smem + (size_t)GL * 512 * 16 + 2048);
    const uint4* h16u4 = (const uint4*)h16;
    float*    x_lds = (float*)(smem + (size_t)GL * 512 * 16 + 2048 + 512);

    const int b   = blockIdx.x;
    const int tid = threadIdx.x;

    // rows tid (i/f half) and tid+512 (g/o half)
    const float* r0 = W_hh + (size_t)tid * HH;
    const float* r1 = W_hh + (size_t)(tid + 512) * HH;

    f16x2 wA[PRW], wB[PRW];
#pragma unroll
    for (int p = 0; p < PRW; ++p) {
        wA[p] = f16x2{(_Float16)r0[2*p], (_Float16)r0[2*p+1]};
        wB[p] = f16x2{(_Float16)r1[2*p], (_Float16)r1[2*p+1]};
    }
#pragma unroll
    for (int g = 0; g < GL; ++g) {
        const int k = KR + 4 * g;
        whh4[g * 512 + tid] = make_uint4(pack2f(r0[k],   r0[k+1]), pack2f(r1[k],   r1[k+1]),
                                         pack2f(r0[k+2], r0[k+3]), pack2f(r1[k+2], r1[k+3]));
    }

    // decode: wave wv, lane l -> o = 8*wv + (l>>3), k-chunk c = l&7 (32 slices each)
    const int lane = tid & 63, wv = tid >> 6;
    const int o = 8 * wv + (lane >> 3), c = lane & 7;
    f16x2 wdec[16];
    {
        const float* wd = W_dec + (size_t)o * 384 + c * 32;
#pragma unroll
        for (int i = 0; i < 16; ++i)
            wdec[i] = f16x2{(_Float16)wd[2*i], (_Float16)wd[2*i+1]};
    }
    const float bdec = b_dec[o];

    float bias0 = 0.f, bias1 = 0.f;
    if (!USE_XP) {
        bias0 = b_ih[tid]       + b_hh[tid];
        bias1 = b_ih[tid + 512] + b_hh[tid + 512];
    }

    float c_state = 0.f;
    if (tid < 256) h16[tid] = (_Float16)0.f;
    __syncthreads();

    const unsigned int* xpb = XPp + (size_t)b * TT * 512;
    const float* xb   = x_seq + (size_t)b * TT * 64;
    float*       outb = out   + (size_t)b * TT * 64;
    const float* wih0 = W_ih + (size_t)tid * 64;
    const float* wih1 = W_ih + (size_t)(tid + 512) * 64;

    unsigned int xpk = 0;
    if (USE_XP) xpk = xpb[tid];                      // t=0

    for (int t = 0; t < TT; ++t) {
        float aA0, aA1 = 0.f, aA2 = 0.f, aA3 = 0.f;
        float aB0, aB1 = 0.f, aB2 = 0.f, aB3 = 0.f;
        unsigned int xpn = 0;

        if (USE_XP) {
            const f16x2 xg = up(xpk);
            aA0 = (float)xg.x; aB0 = (float)xg.y;
            if (t + 1 < TT) xpn = xpb[(size_t)(t + 1) * 512 + tid];   // prefetch
        } else {
            if (tid < 64) x_lds[tid] = xb[t * 64 + tid];
            __syncthreads();
            aA0 = bias0; aB0 = bias1;
            for (int k = 0; k < 64; ++k) {
                const float xv = x_lds[k];
                aA0 += wih0[k] * xv; aB0 += wih1[k] * xv;
            }
        }

        // ---- h @ W_hh^T, register-resident slices [0,184) ----
#pragma unroll
        for (int q = 0; q < QR; ++q) {
            uint4 hv = h16u4[q];
            f16x2 h0 = up(hv.x), h1 = up(hv.y), h2 = up(hv.z), h3 = up(hv.w);
            aA0 = dot2(wA[4*q],   h0, aA0);  aB0 = dot2(wB[4*q],   h0, aB0);
            aA1 = dot2(wA[4*q+1], h1, aA1);  aB1 = dot2(wB[4*q+1], h1, aB1);
            aA2 = dot2(wA[4*q+2], h2, aA2);  aB2 = dot2(wB[4*q+2], h2, aB2);
            aA3 = dot2(wA[4*q+3], h3, aA3);  aB3 = dot2(wB[4*q+3], h3, aB3);
        }
        // ---- h @ W_hh^T, LDS-resident slices [184,256) ----
#pragma unroll
        for (int q = 0; q < QL; ++q) {
            uint4 hv = h16u4[QR + q];
            f16x2 h0 = up(hv.x), h1 = up(hv.y), h2 = up(hv.z), h3 = up(hv.w);
            uint4 w0 = whh4[(2 * q) * 512 + tid];
            aA0 = dot2(up(w0.x), h0, aA0);  aB0 = dot2(up(w0.y), h0, aB0);
            aA1 = dot2(up(w0.z), h1, aA1);  aB1 = dot2(up(w0.w), h1, aB1);
            uint4 w1 = whh4[(2 * q + 1) * 512 + tid];
            aA2 = dot2(up(w1.x), h2, aA2);  aB2 = dot2(up(w1.y), h2, aB2);
            aA3 = dot2(up(w1.z), h3, aA3);  aB3 = dot2(up(w1.w), h3, aB3);
        }
        const float gA = (aA0 + aA1) + (aA2 + aA3);   // i[tid] / f[tid-256]
        const float gB = (aB0 + aB1) + (aB2 + aB3);   // g[tid] / o[tid-256]

        if (tid >= 256) { fo[tid - 256] = gA; fo[tid] = gB; }
        __syncthreads();                               // [A]

        if (tid < 256) {
            const float fg = fo[tid], og = fo[256 + tid];
            const float si = sigf(gA), sf = sigf(fg), so = sigf(og);
            const float tg = tanhfast(gB);
            c_state = sf * c_state + si * tg;
            h16[tid] = (_Float16)(so * tanhfast(c_state));
        }
        __syncthreads();                               // [B]

        // ---- decode: out[t][o] = b_dec[o] + h_t . W_dec[o,:256] ----
        float dacc = 0.f;
#pragma unroll
        for (int i = 0; i < 4; ++i) {
            uint4 hv = h16u4[4 * c + i];
            dacc = dot2(wdec[4*i],   up(hv.x), dacc);
            dacc = dot2(wdec[4*i+1], up(hv.y), dacc);
            dacc = dot2(wdec[4*i+2], up(hv.z), dacc);
            dacc = dot2(wdec[4*i+3], up(hv.w), dacc);
        }
        dacc += __shfl_xor(dacc, 1);
        dacc += __shfl_xor(dacc, 2);
        dacc += __shfl_xor(dacc, 4);
        if (c == 0) outb[t * 64 + o] = dacc + bdec;

        if (USE_XP) xpk = xpn;
        // next iteration's h16/fo writes are fenced by barrier [A] above.
    }
}

extern "C" void kernel_launch(void* const* d_in, const int* in_sizes, int n_in,
                              void* d_out, int out_size, void* d_ws, size_t ws_size,
                              hipStream_t stream) {
    const float* x_seq = (const float*)d_in[0];
    const float* W_ih  = (const float*)d_in[1];
    const float* W_hh  = (const float*)d_in[2];
    const float* b_ih  = (const float*)d_in[3];
    const float* b_hh  = (const float*)d_in[4];
    // d_in[5..8] unused: mem == 0 forever
    const float* W_dec = (const float*)d_in[9];
    const float* b_dec = (const float*)d_in[10];
    float* out = (float*)d_out;

    const size_t smem_bytes = (size_t)GL * 512 * 16 + 2048 + 512 + 256;  // 150272 B
    const size_t xp_bytes   = (size_t)NB * TT * 512 * 4;                 // 67 MB packed

    if (ws_size >= xp_bytes) {
        unsigned int* XPp = (unsigned int*)d_ws;
        hipLaunchKernelGGL(xproj_kernel, dim3(256), dim3(512), 0, stream,
                           x_seq, W_ih, b_ih, b_hh, XPp);
        hipFuncSetAttribute((const void*)&ntm_rec<true>,
                            hipFuncAttributeMaxDynamicSharedMemorySize, (int)smem_bytes);
        hipLaunchKernelGGL(ntm_rec<true>, dim3(NB), dim3(512), smem_bytes, stream,
                           x_seq, W_ih, b_ih, b_hh, XPp, W_hh, W_dec, b_dec, out);
    } else {
        hipFuncSetAttribute((const void*)&ntm_rec<false>,
                            hipFuncAttributeMaxDynamicSharedMemorySize, (int)smem_bytes);
        hipLaunchKernelGGL(ntm_rec<false>, dim3(NB), dim3(512), smem_bytes, stream,
                           x_seq, W_ih, b_ih, b_hh, (const unsigned int*)nullptr,
                           W_hh, W_dec, b_dec, out);
    }
}